// Round 7
// baseline (5717.237 us; speedup 1.0000x reference)
//
#include <hip/hip_runtime.h>

#define B_ 128
#define T_ 256
#define IN_ 256
#define H_ 512
#define G4_ 2048   // 4*H
#define TC_ 16     // time chunk
#define TC_LOG_ 4
#define NCHUNK_ 16

// ---- workspace layout (float offsets) ---- (~48MB total)
static constexpr size_t OFF_XG0 = 0;                                 // B*TC*4H
static constexpr size_t OFF_XG1 = OFF_XG0 + (size_t)B_ * TC_ * G4_;
static constexpr size_t OFF_H0C = OFF_XG1 + (size_t)B_ * TC_ * G4_;  // B*TC*H
static constexpr size_t OFF_HB0 = OFF_H0C + (size_t)B_ * TC_ * H_;   // 2*B*H ping-pong
static constexpr size_t OFF_HB1 = OFF_HB0 + 2 * (size_t)B_ * H_;
static constexpr size_t OFF_C0  = OFF_HB1 + 2 * (size_t)B_ * H_;
static constexpr size_t OFF_C1  = OFF_C0 + (size_t)B_ * H_;
static constexpr size_t OFF_WP0 = OFF_C1 + (size_t)B_ * H_;          // 2048*512
static constexpr size_t OFF_WP1 = OFF_WP0 + (size_t)G4_ * H_;
static constexpr size_t OFF_END = OFF_WP1 + (size_t)G4_ * H_;

// ============================================================================
// Pack W_hh [2048][512] fp32 -> WPK2[ct(32)][k4(128)][g(4)][cl4(16)] float4,
// element = W[g*512 + ct*16 + cl4][k4*4 .. +3].
// ============================================================================
__global__ __launch_bounds__(256) void pack_whh2(
    const float* __restrict__ W, float4* __restrict__ WPK) {
  const int idx = blockIdx.x * 256 + threadIdx.x;  // 0 .. 262143
  const int cl4 = idx & 15;
  const int g   = (idx >> 4) & 3;
  const int k4  = (idx >> 6) & 127;
  const int ct  = idx >> 13;                       // 0..31
  const int row = g * H_ + ct * 16 + cl4;
  WPK[idx] = *(const float4*)(W + (size_t)row * H_ + k4 * 4);
}

// ============================================================================
// GEMM: C[m][n] = sum_k A_row(m)[k] * W[n][k] + bias1[n] + bias2[n]
// ============================================================================
__global__ __launch_bounds__(256) void gemm_xg(
    const float* __restrict__ A, const float* __restrict__ W,
    const float* __restrict__ bias1, const float* __restrict__ bias2,
    float* __restrict__ C, int N, int K, int T_A, int t0) {
  __shared__ float As[32][68];
  __shared__ float Bs[32][68];
  const int tid = threadIdx.x;
  const int m0 = blockIdx.y * 64;
  const int n0 = blockIdx.x * 64;
  const int tx = tid & 15, ty = tid >> 4;
  float acc[4][4] = {};
  for (int k0 = 0; k0 < K; k0 += 32) {
    for (int i = tid; i < 512; i += 256) {
      const int r = i >> 3, k4 = i & 7;
      const int m = m0 + r;
      const int bb = m >> TC_LOG_, tl = m & (TC_ - 1);
      const float4 a4 = *(const float4*)(A + ((size_t)bb * T_A + t0 + tl) * K + k0 + k4 * 4);
      As[k4 * 4 + 0][r] = a4.x; As[k4 * 4 + 1][r] = a4.y;
      As[k4 * 4 + 2][r] = a4.z; As[k4 * 4 + 3][r] = a4.w;
      const float4 b4 = *(const float4*)(W + (size_t)(n0 + r) * K + k0 + k4 * 4);
      Bs[k4 * 4 + 0][r] = b4.x; Bs[k4 * 4 + 1][r] = b4.y;
      Bs[k4 * 4 + 2][r] = b4.z; Bs[k4 * 4 + 3][r] = b4.w;
    }
    __syncthreads();
#pragma unroll
    for (int k = 0; k < 32; ++k) {
      const float4 av = *(const float4*)&As[k][ty * 4];
      const float4 bv = *(const float4*)&Bs[k][tx * 4];
      const float ar[4] = {av.x, av.y, av.z, av.w};
      const float br[4] = {bv.x, bv.y, bv.z, bv.w};
#pragma unroll
      for (int ii = 0; ii < 4; ++ii)
#pragma unroll
        for (int jj = 0; jj < 4; ++jj)
          acc[ii][jj] = fmaf(ar[ii], br[jj], acc[ii][jj]);
    }
    __syncthreads();
  }
  const int col0 = n0 + tx * 4;
  float bsum[4];
#pragma unroll
  for (int jj = 0; jj < 4; ++jj) bsum[jj] = bias1[col0 + jj] + bias2[col0 + jj];
#pragma unroll
  for (int ii = 0; ii < 4; ++ii) {
    float4 o;
    o.x = acc[ii][0] + bsum[0]; o.y = acc[ii][1] + bsum[1];
    o.z = acc[ii][2] + bsum[2]; o.w = acc[ii][3] + bsum[3];
    *(float4*)(C + (size_t)(m0 + ty * 4 + ii) * N + col0) = o;
  }
}

// ============================================================================
// Fused 2-layer LSTM step, LDS-balanced tiling.
// mode 0: 256 blocks (both layers). mode 1: 128 blocks L0. mode 2: 128 L1.
// Block: (xcd=bid&7) -> ct = xcd*4+ctl (XCD-clustered weight slices, L2-res).
// Block tile: 32 batches x 16 hcols x 4 gates. Thread (kq=wave 0..3,
// bt4 0..7, cl2 0..7): 4 batches x 2 hcols x 4 gates over a k-quarter.
// Per k: 4 LDS b128 + 8 weight b128 -> 256 lane-FMA (2.0 FMA/LDS-byte).
// kq-reduce via transposed scalar LDS aliased onto the h tile (after barrier).
// ============================================================================
#define DOT4(dst, wv, hv)                 \
  dst = fmaf(wv.x, hv.x, dst); dst = fmaf(wv.y, hv.y, dst); \
  dst = fmaf(wv.z, hv.z, dst); dst = fmaf(wv.w, hv.w, dst);

__global__ __launch_bounds__(256) void lstm_step2(
    const float4* __restrict__ W0, const float* __restrict__ xg0,
    const float* __restrict__ h0p, float* __restrict__ h0n,
    float* __restrict__ cs0, float* __restrict__ hdump,
    const float4* __restrict__ W1, const float* __restrict__ xg1,
    const float* __restrict__ h1p, float* __restrict__ h1n,
    float* __restrict__ cs1, int tl, int mode) {
  __shared__ float4 hl4[32 * 128];   // 64KB h tile; red[] aliases it later
  float* red = (float*)hl4;          // [3][32][64] floats = 24KB
  const int bid = blockIdx.x;
  const int xcd = bid & 7;
  int li = bid >> 3;
  int layer;
  if (mode == 0) { layer = li >> 4; li &= 15; } else { layer = mode - 1; }
  const int bt  = li & 3;
  const int ctl = (li >> 2) & 3;
  const int ct  = xcd * 4 + ctl;

  const float4* WPK; const float* xg; const float* hprev;
  float* hnext; float* cst; float* hdmp;
  if (layer == 0) { WPK = W0; xg = xg0; hprev = h0p; hnext = h0n; cst = cs0; hdmp = hdump; }
  else            { WPK = W1; xg = xg1; hprev = h1p; hnext = h1n; cst = cs1; hdmp = nullptr; }

  const int tid = threadIdx.x;
  const int kq   = tid >> 6;           // wave id = k quarter (uniform branches)
  const int lane = tid & 63;
  const int bt4  = lane & 7;           // 4 batches each
  const int cl2  = lane >> 3;          // 2 hcols each
  const int b0   = bt * 32;
  const int hcol0 = ct * 16 + cl2 * 2;

  // wave 0: prefetch xg and c into registers (latency hides under staging+FMA)
  float xgv[2][4][4], cc[2][4];
  if (kq == 0) {
#pragma unroll
    for (int hc = 0; hc < 2; ++hc)
#pragma unroll
      for (int i = 0; i < 4; ++i) {
        const int b = b0 + bt4 * 4 + i;
        const float* xr = xg + ((size_t)b * TC_ + tl) * G4_ + hcol0 + hc;
        xgv[hc][0][i] = xr[0];
        xgv[hc][1][i] = xr[512];
        xgv[hc][2][i] = xr[1024];
        xgv[hc][3][i] = xr[1536];
        cc[hc][i] = cst[(size_t)b * H_ + hcol0 + hc];
      }
  }
  // stage h tile: 32 rows x 128 float4, swizzled col' = k4 ^ (row>>2)
  const float4* hsrc = (const float4*)hprev + (size_t)b0 * 128;
#pragma unroll
  for (int j = 0; j < 16; ++j) {
    const int idx = tid + j * 256;   // 0..4095
    const int r = idx >> 7, k4 = idx & 127;
    hl4[r * 128 + (k4 ^ (r >> 2))] = hsrc[idx];
  }
  __syncthreads();

  // 32 register accumulators: a[hc][gate][batch], k range = quarter
  float a[2][4][4] = {};
  const float4* hb = hl4 + (size_t)(bt4 * 4) * 128;
  const float4* wp = WPK + ((size_t)ct * 128 + kq * 32) * 64 + cl2 * 2;
#pragma unroll 2
  for (int k = 0; k < 32; ++k) {
    const int kx = (kq * 32 + k) ^ bt4;
    const float4 h0 = hb[0 * 128 + kx];
    const float4 h1 = hb[1 * 128 + kx];
    const float4 h2 = hb[2 * 128 + kx];
    const float4 h3 = hb[3 * 128 + kx];
    const float4* wk = wp + (size_t)k * 64;
#pragma unroll
    for (int g = 0; g < 4; ++g) {
      const float4 wA = wk[g * 16];
      const float4 wB = wk[g * 16 + 1];
      DOT4(a[0][g][0], wA, h0) DOT4(a[0][g][1], wA, h1)
      DOT4(a[0][g][2], wA, h2) DOT4(a[0][g][3], wA, h3)
      DOT4(a[1][g][0], wB, h0) DOT4(a[1][g][1], wB, h1)
      DOT4(a[1][g][2], wB, h2) DOT4(a[1][g][3], wB, h3)
    }
  }
  __syncthreads();   // hl4 reads done -> safe to alias as red
  if (kq != 0) {
    const int qb = (kq - 1) * 32 * 64;
#pragma unroll
    for (int hc = 0; hc < 2; ++hc)
#pragma unroll
      for (int g = 0; g < 4; ++g)
#pragma unroll
        for (int i = 0; i < 4; ++i)
          red[qb + ((hc * 4 + g) * 4 + i) * 64 + lane] = a[hc][g][i];
  }
  __syncthreads();
  if (kq == 0) {
#pragma unroll
    for (int hc = 0; hc < 2; ++hc)
#pragma unroll
      for (int g = 0; g < 4; ++g)
#pragma unroll
        for (int i = 0; i < 4; ++i) {
          const int j = ((hc * 4 + g) * 4 + i) * 64 + lane;
          a[hc][g][i] += red[j] + red[32 * 64 + j] + red[2 * 32 * 64 + j];
        }
#pragma unroll
    for (int hc = 0; hc < 2; ++hc)
#pragma unroll
      for (int i = 0; i < 4; ++i) {
        const int b = b0 + bt4 * 4 + i;
        const int hcol = hcol0 + hc;
        const float gi = a[hc][0][i] + xgv[hc][0][i];
        const float gf = a[hc][1][i] + xgv[hc][1][i];
        const float gg = a[hc][2][i] + xgv[hc][2][i];
        const float go = a[hc][3][i] + xgv[hc][3][i];
        const float iv = 1.f / (1.f + __expf(-gi));
        const float fv = 1.f / (1.f + __expf(-gf));
        const float gv = tanhf(gg);
        const float ov = 1.f / (1.f + __expf(-go));
        const float cn = fv * cc[hc][i] + iv * gv;
        const float hv = ov * tanhf(cn);
        cst[(size_t)b * H_ + hcol] = cn;
        hnext[(size_t)b * H_ + hcol] = hv;
        if (hdmp) hdmp[((size_t)b * TC_ + tl) * H_ + hcol] = hv;
      }
  }
}

// ============================================================================
// Final FC (10 classes) + log_softmax. One wave per batch row.
// ============================================================================
__global__ __launch_bounds__(64) void fc_logsoftmax(
    const float* __restrict__ h, const float* __restrict__ Wfc,
    const float* __restrict__ bfc, float* __restrict__ out) {
  const int b = blockIdx.x, lane = threadIdx.x;
  const float4* h4 = (const float4*)(h + (size_t)b * H_);
  const float4 hv0 = h4[lane * 2], hv1 = h4[lane * 2 + 1];
  float logits[10];
#pragma unroll
  for (int cc = 0; cc < 10; ++cc) {
    const float4* w4 = (const float4*)(Wfc + (size_t)cc * H_);
    const float4 w0 = w4[lane * 2], w1 = w4[lane * 2 + 1];
    float v = hv0.x * w0.x + hv0.y * w0.y + hv0.z * w0.z + hv0.w * w0.w +
              hv1.x * w1.x + hv1.y * w1.y + hv1.z * w1.z + hv1.w * w1.w;
#pragma unroll
    for (int off = 32; off; off >>= 1) v += __shfl_xor(v, off);
    logits[cc] = v + bfc[cc];
  }
  float m = logits[0];
#pragma unroll
  for (int cc = 1; cc < 10; ++cc) m = fmaxf(m, logits[cc]);
  float s = 0.f;
#pragma unroll
  for (int cc = 0; cc < 10; ++cc) s += __expf(logits[cc] - m);
  const float lse = m + __logf(s);
  if (lane < 10) out[(size_t)b * 10 + lane] = logits[lane] - lse;
}

// ============================================================================
extern "C" void kernel_launch(void* const* d_in, const int* in_sizes, int n_in,
                              void* d_out, int out_size, void* d_ws, size_t ws_size,
                              hipStream_t stream) {
  const float* x    = (const float*)d_in[0];
  const float* Wih0 = (const float*)d_in[1];
  const float* Whh0 = (const float*)d_in[2];
  const float* bih0 = (const float*)d_in[3];
  const float* bhh0 = (const float*)d_in[4];
  const float* Wih1 = (const float*)d_in[5];
  const float* Whh1 = (const float*)d_in[6];
  const float* bih1 = (const float*)d_in[7];
  const float* bhh1 = (const float*)d_in[8];
  const float* Wfc  = (const float*)d_in[9];
  const float* bfc  = (const float*)d_in[10];

  float* ws   = (float*)d_ws;
  float* XG0  = ws + OFF_XG0;
  float* XG1  = ws + OFF_XG1;
  float* h0c  = ws + OFF_H0C;
  float* hb0  = ws + OFF_HB0;
  float* hb1  = ws + OFF_HB1;
  float* c0   = ws + OFF_C0;
  float* c1   = ws + OFF_C1;
  float4* wp0 = (float4*)(ws + OFF_WP0);
  float4* wp1 = (float4*)(ws + OFF_WP1);

  // zero h ping-pong + c state every launch; pack recurrent weights
  hipMemsetAsync(hb0, 0, (OFF_WP0 - OFF_HB0) * sizeof(float), stream);
  pack_whh2<<<1024, 256, 0, stream>>>(Whh0, wp0);
  pack_whh2<<<1024, 256, 0, stream>>>(Whh1, wp1);

  const size_t BH = (size_t)B_ * H_;
  const dim3 ggrid(G4_ / 64, (B_ * TC_) / 64);  // (32, 32)
  for (int ch = 0; ch < NCHUNK_; ++ch) {
    const int t0 = ch * TC_;
    gemm_xg<<<ggrid, 256, 0, stream>>>(x, Wih0, bih0, bhh0, XG0, G4_, IN_, T_, t0);
    if (ch > 0)
      gemm_xg<<<ggrid, 256, 0, stream>>>(h0c, Wih1, bih1, bhh1, XG1, G4_, H_, TC_, 0);
    for (int t = 0; t < TC_; ++t) {
      const int sg0 = t0 + t + 1;        // L0 global step (1-based)
      const int sg1 = sg0 - TC_;         // L1 global step (prev chunk)
      const int mode = (ch == 0) ? 1 : 0;
      const int nblk = (ch == 0) ? 128 : 256;
      lstm_step2<<<nblk, 256, 0, stream>>>(
          wp0, XG0, hb0 + ((sg0 - 1) & 1) * BH, hb0 + (sg0 & 1) * BH, c0, h0c,
          wp1, XG1, hb1 + (((sg1 - 1) & 1)) * BH, hb1 + ((sg1 & 1)) * BH, c1,
          t, mode);
    }
  }
  // pipeline drain: L1 over the last chunk
  gemm_xg<<<ggrid, 256, 0, stream>>>(h0c, Wih1, bih1, bhh1, XG1, G4_, H_, TC_, 0);
  for (int t = 0; t < TC_; ++t) {
    const int sg1 = (NCHUNK_ - 1) * TC_ + t + 1;
    lstm_step2<<<128, 256, 0, stream>>>(
        wp0, XG0, hb0, hb0, c0, h0c,
        wp1, XG1, hb1 + ((sg1 - 1) & 1) * BH, hb1 + (sg1 & 1) * BH, c1,
        t, 2);
  }
  // T=256 even -> final h1 in slot 0
  fc_logsoftmax<<<dim3(B_), 64, 0, stream>>>(hb1, Wfc, bfc, (float*)d_out);
}

// Round 8
// 2726.749 us; speedup vs baseline: 2.0967x; 2.0967x over previous
//
#include <hip/hip_runtime.h>

#define B_ 128
#define T_ 256
#define IN_ 256
#define H_ 512
#define G4_ 2048   // 4*H
#define TC_ 16     // time chunk
#define TC_LOG_ 4
#define NCHUNK_ 16

typedef __attribute__((ext_vector_type(8))) short short8v;   // 8 bf16
typedef __attribute__((ext_vector_type(4))) float float4v;

// ---- workspace layout (float offsets) ---- (~43MB total)
static constexpr size_t OFF_XG0 = 0;                                 // B*TC*4H
static constexpr size_t OFF_XG1 = OFF_XG0 + (size_t)B_ * TC_ * G4_;
static constexpr size_t OFF_H0C = OFF_XG1 + (size_t)B_ * TC_ * G4_;  // B*TC*H fp32
static constexpr size_t OFF_HB0 = OFF_H0C + (size_t)B_ * TC_ * H_;   // 2*B*H bf16 = B*H floats/2... (alloc B*H floats/2*2)
static constexpr size_t OFF_HB1 = OFF_HB0 + (size_t)B_ * H_;         // (2 slots x B*H ushort = B*H floats)
static constexpr size_t OFF_C0  = OFF_HB1 + (size_t)B_ * H_;         // B*H fp32
static constexpr size_t OFF_C1  = OFF_C0 + (size_t)B_ * H_;
static constexpr size_t OFF_H1F = OFF_C1 + (size_t)B_ * H_;          // B*H fp32
static constexpr size_t OFF_WF0 = OFF_H1F + (size_t)B_ * H_;         // 2048*512 bf16 = 524288 floats
static constexpr size_t OFF_WF1 = OFF_WF0 + (size_t)G4_ * H_ / 2;
static constexpr size_t OFF_END = OFF_WF1 + (size_t)G4_ * H_ / 2;

// bf16 round-to-nearest-even from fp32
__device__ __forceinline__ unsigned int bfr(float f) {
  unsigned int u = __float_as_uint(f);
  return (u + 0x7fffu + ((u >> 16) & 1u)) >> 16;
}

// ============================================================================
// Pack W_hh [2048][512] fp32 -> bf16 MFMA B-fragments.
// Fragment (ct,g,ks): 16 hcols x 32 k. Lane l holds W[g*512+ct*16+(l&15)]
// [ks*32+(l>>4)*8 .. +7]. Stored lane-major: wave reads 1KB contiguous.
// ============================================================================
__global__ __launch_bounds__(256) void pack_whh3(
    const float* __restrict__ W, uint4* __restrict__ WF) {
  const int idx = blockIdx.x * 256 + threadIdx.x;  // 0..131071
  const int l  = idx & 63;
  const int ks = (idx >> 6) & 15;
  const int g  = (idx >> 10) & 3;
  const int ct = idx >> 12;                        // 0..31
  const int row = g * H_ + ct * 16 + (l & 15);
  const int k0  = ks * 32 + (l >> 4) * 8;
  const float* s = W + (size_t)row * H_ + k0;
  uint4 o;
  o.x = bfr(s[0]) | (bfr(s[1]) << 16);
  o.y = bfr(s[2]) | (bfr(s[3]) << 16);
  o.z = bfr(s[4]) | (bfr(s[5]) << 16);
  o.w = bfr(s[6]) | (bfr(s[7]) << 16);
  WF[idx] = o;
}

// ============================================================================
// GEMM: C[m][n] = sum_k A_row(m)[k] * W[n][k] + bias1[n] + bias2[n]
// ============================================================================
__global__ __launch_bounds__(256) void gemm_xg(
    const float* __restrict__ A, const float* __restrict__ W,
    const float* __restrict__ bias1, const float* __restrict__ bias2,
    float* __restrict__ C, int N, int K, int T_A, int t0) {
  __shared__ float As[32][68];
  __shared__ float Bs[32][68];
  const int tid = threadIdx.x;
  const int m0 = blockIdx.y * 64;
  const int n0 = blockIdx.x * 64;
  const int tx = tid & 15, ty = tid >> 4;
  float acc[4][4] = {};
  for (int k0 = 0; k0 < K; k0 += 32) {
    for (int i = tid; i < 512; i += 256) {
      const int r = i >> 3, k4 = i & 7;
      const int m = m0 + r;
      const int bb = m >> TC_LOG_, tl = m & (TC_ - 1);
      const float4 a4 = *(const float4*)(A + ((size_t)bb * T_A + t0 + tl) * K + k0 + k4 * 4);
      As[k4 * 4 + 0][r] = a4.x; As[k4 * 4 + 1][r] = a4.y;
      As[k4 * 4 + 2][r] = a4.z; As[k4 * 4 + 3][r] = a4.w;
      const float4 b4 = *(const float4*)(W + (size_t)(n0 + r) * K + k0 + k4 * 4);
      Bs[k4 * 4 + 0][r] = b4.x; Bs[k4 * 4 + 1][r] = b4.y;
      Bs[k4 * 4 + 2][r] = b4.z; Bs[k4 * 4 + 3][r] = b4.w;
    }
    __syncthreads();
#pragma unroll
    for (int k = 0; k < 32; ++k) {
      const float4 av = *(const float4*)&As[k][ty * 4];
      const float4 bv = *(const float4*)&Bs[k][tx * 4];
      const float ar[4] = {av.x, av.y, av.z, av.w};
      const float br[4] = {bv.x, bv.y, bv.z, bv.w};
#pragma unroll
      for (int ii = 0; ii < 4; ++ii)
#pragma unroll
        for (int jj = 0; jj < 4; ++jj)
          acc[ii][jj] = fmaf(ar[ii], br[jj], acc[ii][jj]);
    }
    __syncthreads();
  }
  const int col0 = n0 + tx * 4;
  float bsum[4];
#pragma unroll
  for (int jj = 0; jj < 4; ++jj) bsum[jj] = bias1[col0 + jj] + bias2[col0 + jj];
#pragma unroll
  for (int ii = 0; ii < 4; ++ii) {
    float4 o;
    o.x = acc[ii][0] + bsum[0]; o.y = acc[ii][1] + bsum[1];
    o.z = acc[ii][2] + bsum[2]; o.w = acc[ii][3] + bsum[3];
    *(float4*)(C + (size_t)(m0 + ty * 4 + ii) * N + col0) = o;
  }
}

// ============================================================================
// Fused 2-layer MFMA LSTM step. mode 0: 512 blocks (L0+L1); 1: 256 L0; 2: 256 L1.
// Block bid: xcd=bid&7, ctl=(bid>>3)&3, bt=(bid>>5)&7, layer=bid>>8 (mode 0).
// Tile: 16 batches x 16 hcols x 4 gates. Wave g computes gate g's 16x16 D via
// 16 x mfma_f32_16x16x32_bf16 (K=512). h bf16 in LDS (swizzled); W bf16
// fragments streamed from XCD-local L2 (512KB set). Tail: gates through LDS,
// fp32 activations, bf16 h store (+fp32 dumps for L1-GEMM input / final fc).
// ============================================================================
__global__ __launch_bounds__(256) void lstm_step2(
    const short8v* __restrict__ WF0, const float* __restrict__ xg0,
    const unsigned short* __restrict__ h0p, unsigned short* __restrict__ h0n,
    float* __restrict__ cs0, float* __restrict__ h0c,
    const short8v* __restrict__ WF1, const float* __restrict__ xg1,
    const unsigned short* __restrict__ h1p, unsigned short* __restrict__ h1n,
    float* __restrict__ cs1, float* __restrict__ h1f, int tl, int mode) {
  __shared__ unsigned short hsh[16 * 512];  // 16KB h tile (bf16, chunk-swizzled)
  __shared__ float gl[4][16][17];           // gate tiles for tail
  const int bid = blockIdx.x;
  const int layer = (mode == 0) ? (bid >> 8) : (mode - 1);
  const int xcd = bid & 7;
  const int ctl = (bid >> 3) & 3;
  const int bt  = (bid >> 5) & 7;
  const int ct  = xcd * 4 + ctl;
  const int b0  = bt * 16;

  const short8v* WF; const float* xg; const unsigned short* hprev;
  unsigned short* hnext; float* cst;
  if (layer == 0) { WF = WF0; xg = xg0; hprev = h0p; hnext = h0n; cst = cs0; }
  else            { WF = WF1; xg = xg1; hprev = h1p; hnext = h1n; cst = cs1; }

  const int tid = threadIdx.x;
  // tail identity (also used for prefetch)
  const int tb = tid >> 4, thc = tid & 15;
  const int bb = b0 + tb;
  const int hcol = ct * 16 + thc;
  const float* xr = xg + ((size_t)bb * TC_ + tl) * G4_ + hcol;
  const float xi = xr[0], xf = xr[512], xgv = xr[1024], xo = xr[1536];
  const float cin = cst[(size_t)bb * H_ + hcol];

  // stage h tile: 16 rows x 64 chunks(16B bf16x8), swizzle chunk c -> c^(r&7)
  const uint4* hp4 = (const uint4*)hprev + (size_t)b0 * 64;
#pragma unroll
  for (int j = 0; j < 4; ++j) {
    const int idx = tid + j * 256;           // 0..1023
    const int r = idx >> 6, c = idx & 63;
    *(uint4*)&hsh[(r * 64 + (c ^ (r & 7))) * 8] = hp4[(size_t)r * 64 + c];
  }
  __syncthreads();

  // MFMA: wave g -> gate g's 16x16 tile, K = 512
  const int lane = tid & 63;
  const int g = tid >> 6;
  const int ar = lane & 15;                  // A row (batch in tile)
  const int koct = lane >> 4;                // k-octet
  float4v acc = {0.f, 0.f, 0.f, 0.f};
  const short8v* wf = WF + ((size_t)(ct * 4 + g) * 16) * 64 + lane;
#pragma unroll
  for (int ks = 0; ks < 16; ++ks) {
    const int c16 = ks * 4 + koct;
    const short8v av = *(const short8v*)&hsh[(ar * 64 + (c16 ^ (ar & 7))) * 8];
    const short8v bv = wf[(size_t)ks * 64];
    acc = __builtin_amdgcn_mfma_f32_16x16x32_bf16(av, bv, acc, 0, 0, 0);
  }
  // D layout: col = lane&15, row = (lane>>4)*4 + reg  (row = batch)
  const int drow = (lane >> 4) * 4, dcol = lane & 15;
#pragma unroll
  for (int rr = 0; rr < 4; ++rr) gl[g][drow + rr][dcol] = acc[rr];
  __syncthreads();

  // tail: thread (tb, thc) combines 4 gates
  {
    const float gi = gl[0][tb][thc] + xi;
    const float gf = gl[1][tb][thc] + xf;
    const float gg = gl[2][tb][thc] + xgv;
    const float go = gl[3][tb][thc] + xo;
    const float iv = 1.f / (1.f + __expf(-gi));
    const float fv = 1.f / (1.f + __expf(-gf));
    const float gv = tanhf(gg);
    const float ov = 1.f / (1.f + __expf(-go));
    const float cn = fv * cin + iv * gv;
    const float hv = ov * tanhf(cn);
    cst[(size_t)bb * H_ + hcol] = cn;
    hnext[(size_t)bb * H_ + hcol] = (unsigned short)bfr(hv);
    if (layer == 0) h0c[((size_t)bb * TC_ + tl) * H_ + hcol] = hv;
    else            h1f[(size_t)bb * H_ + hcol] = hv;
  }
}

// ============================================================================
// Final FC (10 classes) + log_softmax. One wave per batch row (fp32 h).
// ============================================================================
__global__ __launch_bounds__(64) void fc_logsoftmax(
    const float* __restrict__ h, const float* __restrict__ Wfc,
    const float* __restrict__ bfc, float* __restrict__ out) {
  const int b = blockIdx.x, lane = threadIdx.x;
  const float4* h4 = (const float4*)(h + (size_t)b * H_);
  const float4 hv0 = h4[lane * 2], hv1 = h4[lane * 2 + 1];
  float logits[10];
#pragma unroll
  for (int cc = 0; cc < 10; ++cc) {
    const float4* w4 = (const float4*)(Wfc + (size_t)cc * H_);
    const float4 w0 = w4[lane * 2], w1 = w4[lane * 2 + 1];
    float v = hv0.x * w0.x + hv0.y * w0.y + hv0.z * w0.z + hv0.w * w0.w +
              hv1.x * w1.x + hv1.y * w1.y + hv1.z * w1.z + hv1.w * w1.w;
#pragma unroll
    for (int off = 32; off; off >>= 1) v += __shfl_xor(v, off);
    logits[cc] = v + bfc[cc];
  }
  float m = logits[0];
#pragma unroll
  for (int cc = 1; cc < 10; ++cc) m = fmaxf(m, logits[cc]);
  float s = 0.f;
#pragma unroll
  for (int cc = 0; cc < 10; ++cc) s += __expf(logits[cc] - m);
  const float lse = m + __logf(s);
  if (lane < 10) out[(size_t)b * 10 + lane] = logits[lane] - lse;
}

// ============================================================================
extern "C" void kernel_launch(void* const* d_in, const int* in_sizes, int n_in,
                              void* d_out, int out_size, void* d_ws, size_t ws_size,
                              hipStream_t stream) {
  const float* x    = (const float*)d_in[0];
  const float* Wih0 = (const float*)d_in[1];
  const float* Whh0 = (const float*)d_in[2];
  const float* bih0 = (const float*)d_in[3];
  const float* bhh0 = (const float*)d_in[4];
  const float* Wih1 = (const float*)d_in[5];
  const float* Whh1 = (const float*)d_in[6];
  const float* bih1 = (const float*)d_in[7];
  const float* bhh1 = (const float*)d_in[8];
  const float* Wfc  = (const float*)d_in[9];
  const float* bfc  = (const float*)d_in[10];

  float* ws   = (float*)d_ws;
  float* XG0  = ws + OFF_XG0;
  float* XG1  = ws + OFF_XG1;
  float* h0c  = ws + OFF_H0C;
  unsigned short* hb0 = (unsigned short*)(ws + OFF_HB0);  // 2 slots x B*H bf16
  unsigned short* hb1 = (unsigned short*)(ws + OFF_HB1);
  float* c0   = ws + OFF_C0;
  float* c1   = ws + OFF_C1;
  float* h1f  = ws + OFF_H1F;
  short8v* wf0 = (short8v*)(ws + OFF_WF0);
  short8v* wf1 = (short8v*)(ws + OFF_WF1);

  // zero h ping-pong (bf16 0 == 0x0000) + c state; pack recurrent weights
  hipMemsetAsync(hb0, 0, (OFF_H1F - OFF_HB0) * sizeof(float), stream);
  pack_whh3<<<512, 256, 0, stream>>>(Whh0, (uint4*)wf0);
  pack_whh3<<<512, 256, 0, stream>>>(Whh1, (uint4*)wf1);

  const size_t BHu = (size_t)B_ * H_;  // slot stride in ushorts
  const dim3 ggrid(G4_ / 64, (B_ * TC_) / 64);  // (32, 32)
  for (int ch = 0; ch < NCHUNK_; ++ch) {
    const int t0 = ch * TC_;
    gemm_xg<<<ggrid, 256, 0, stream>>>(x, Wih0, bih0, bhh0, XG0, G4_, IN_, T_, t0);
    if (ch > 0)
      gemm_xg<<<ggrid, 256, 0, stream>>>(h0c, Wih1, bih1, bhh1, XG1, G4_, H_, TC_, 0);
    for (int t = 0; t < TC_; ++t) {
      const int sg0 = t0 + t + 1;        // L0 global step (1-based)
      const int sg1 = sg0 - TC_;         // L1 global step (prev chunk)
      const int mode = (ch == 0) ? 1 : 0;
      const int nblk = (ch == 0) ? 256 : 512;
      lstm_step2<<<nblk, 256, 0, stream>>>(
          wf0, XG0, hb0 + ((sg0 - 1) & 1) * BHu, hb0 + (sg0 & 1) * BHu, c0, h0c,
          wf1, XG1, hb1 + ((sg1 - 1) & 1) * BHu, hb1 + (sg1 & 1) * BHu, c1, h1f,
          t, mode);
    }
  }
  // pipeline drain: L1 over the last chunk
  gemm_xg<<<ggrid, 256, 0, stream>>>(h0c, Wih1, bih1, bhh1, XG1, G4_, H_, TC_, 0);
  for (int t = 0; t < TC_; ++t) {
    const int sg1 = (NCHUNK_ - 1) * TC_ + t + 1;
    lstm_step2<<<256, 256, 0, stream>>>(
        wf0, XG0, hb0, hb0, c0, h0c,
        wf1, XG1, hb1 + ((sg1 - 1) & 1) * BHu, hb1 + (sg1 & 1) * BHu, c1, h1f,
        t, 2);
  }
  fc_logsoftmax<<<dim3(B_), 64, 0, stream>>>(h1f, Wfc, bfc, (float*)d_out);
}

// Round 9
// 1689.804 us; speedup vs baseline: 3.3834x; 1.6136x over previous
//
#include <hip/hip_runtime.h>

#define B_ 128
#define T_ 256
#define IN_ 256
#define H_ 512
#define G4_ 2048   // 4*H
#define TC_ 16     // time chunk
#define TC_LOG_ 4
#define NCHUNK_ 16

typedef __attribute__((ext_vector_type(8))) short short8v;   // 8 bf16
typedef __attribute__((ext_vector_type(4))) float float4v;

// ---- workspace layout (float offsets) ---- (~61MB total)
static constexpr size_t OFF_XG0 = 0;                                  // B*TC*4H fp32
static constexpr size_t OFF_XG1 = OFF_XG0 + (size_t)B_ * TC_ * G4_;
static constexpr size_t OFF_H0C = OFF_XG1 + (size_t)B_ * TC_ * G4_;   // B*TC*H bf16
static constexpr size_t OFF_HB0 = OFF_H0C + (size_t)B_ * TC_ * H_ / 2;// 2 slots B*H bf16
static constexpr size_t OFF_HB1 = OFF_HB0 + (size_t)B_ * H_;
static constexpr size_t OFF_C0  = OFF_HB1 + (size_t)B_ * H_;          // B*H fp32
static constexpr size_t OFF_C1  = OFF_C0 + (size_t)B_ * H_;
static constexpr size_t OFF_H1F = OFF_C1 + (size_t)B_ * H_;           // B*H fp32
static constexpr size_t OFF_WF0 = OFF_H1F + (size_t)B_ * H_;          // W_hh0 bf16 frags
static constexpr size_t OFF_WF1 = OFF_WF0 + (size_t)G4_ * H_ / 2;
static constexpr size_t OFF_WI0 = OFF_WF1 + (size_t)G4_ * H_ / 2;     // W_ih0 bf16 frags (K=256)
static constexpr size_t OFF_WI1 = OFF_WI0 + (size_t)G4_ * IN_ / 2;    // W_ih1 bf16 frags (K=512)
static constexpr size_t OFF_XBF = OFF_WI1 + (size_t)G4_ * H_ / 2;     // x bf16
static constexpr size_t OFF_END = OFF_XBF + (size_t)B_ * T_ * IN_ / 2;

// bf16 round-to-nearest-even from fp32
__device__ __forceinline__ unsigned int bfr(float f) {
  unsigned int u = __float_as_uint(f);
  return (u + 0x7fffu + ((u >> 16) & 1u)) >> 16;
}

// ============================================================================
// Convert fp32 -> bf16, 8 elems/thread (for x).
// ============================================================================
__global__ __launch_bounds__(256) void conv_bf16(
    const float* __restrict__ in, uint4* __restrict__ out, int n8) {
  const int idx = blockIdx.x * 256 + threadIdx.x;
  if (idx >= n8) return;
  const float4 a = *(const float4*)(in + (size_t)idx * 8);
  const float4 b = *(const float4*)(in + (size_t)idx * 8 + 4);
  uint4 o;
  o.x = bfr(a.x) | (bfr(a.y) << 16);
  o.y = bfr(a.z) | (bfr(a.w) << 16);
  o.z = bfr(b.x) | (bfr(b.y) << 16);
  o.w = bfr(b.z) | (bfr(b.w) << 16);
  out[idx] = o;
}

// ============================================================================
// Pack W_hh [2048][512] fp32 -> bf16 MFMA B-fragments, gate-tiled order
// (ct,g,ks): lane l holds W[g*512+ct*16+(l&15)][ks*32+(l>>4)*8 .. +7].
// ============================================================================
__global__ __launch_bounds__(256) void pack_whh3(
    const float* __restrict__ W, uint4* __restrict__ WF) {
  const int idx = blockIdx.x * 256 + threadIdx.x;  // 0..131071
  const int l  = idx & 63;
  const int ks = (idx >> 6) & 15;
  const int g  = (idx >> 10) & 3;
  const int ct = idx >> 12;                        // 0..31
  const int row = g * H_ + ct * 16 + (l & 15);
  const int k0  = ks * 32 + (l >> 4) * 8;
  const float* s = W + (size_t)row * H_ + k0;
  uint4 o;
  o.x = bfr(s[0]) | (bfr(s[1]) << 16);
  o.y = bfr(s[2]) | (bfr(s[3]) << 16);
  o.z = bfr(s[4]) | (bfr(s[5]) << 16);
  o.w = bfr(s[6]) | (bfr(s[7]) << 16);
  WF[idx] = o;
}

// ============================================================================
// Pack W_ih [2048][K] fp32 -> bf16 MFMA B-fragments, plain n-tile order:
// frag (nt, ks): lane l holds W[nt*16+(l&15)][ks*32+(l>>4)*8 .. +7].
// ============================================================================
__global__ __launch_bounds__(256) void pack_wih(
    const float* __restrict__ W, uint4* __restrict__ WF, int K) {
  const int idx = blockIdx.x * 256 + threadIdx.x;  // nt*ksn*64 total
  const int ksn = K >> 5;
  const int l  = idx & 63;
  const int ks = (idx >> 6) & (ksn - 1);
  const int nt = idx >> 6 >> (K == 512 ? 4 : 3);
  const int row = nt * 16 + (l & 15);
  const int k0  = ks * 32 + (l >> 4) * 8;
  const float* s = W + (size_t)row * K + k0;
  uint4 o;
  o.x = bfr(s[0]) | (bfr(s[1]) << 16);
  o.y = bfr(s[2]) | (bfr(s[3]) << 16);
  o.z = bfr(s[4]) | (bfr(s[5]) << 16);
  o.w = bfr(s[6]) | (bfr(s[7]) << 16);
  WF[idx] = o;
}

// ============================================================================
// MFMA GEMM: C[m][n] = sum_k A_row(m)[k]*W[n][k] + bias1[n] + bias2[n]
// A bf16 row-major [.][K]; row(m) = (m>>4)*T_A + t0 + (m&15). C fp32 [2048].
// M=2048, N=2048. Grid 1024: xcd=bid&7, nb=xcd*4+(q&3), mb=q>>2 (q=bid>>3)
// -> per-XCD B-slice 256 cols (<=256KB bf16, L2-resident).
// Block 64x64, 4 waves; wave w = cols n0+w*16, 4 row-blocks, K-loop MFMA.
// A staged 64 rows x K bf16 in LDS, chunk-swizzled c^(r&7) (2-way free).
// ============================================================================
__global__ __launch_bounds__(256) void gemm_xg_mfma(
    const unsigned short* __restrict__ A, const short8v* __restrict__ WF,
    const float* __restrict__ bias1, const float* __restrict__ bias2,
    float* __restrict__ C, int K, int T_A, int t0) {
  __shared__ uint4 Ash[64 * 64];       // 64KB max (uses 64*(K/8))
  const int bid = blockIdx.x;
  const int xcd = bid & 7;
  const int q   = bid >> 3;
  const int n0  = (xcd * 4 + (q & 3)) * 64;
  const int m0  = (q >> 2) * 64;
  const int tid = threadIdx.x;
  const int ch  = K >> 3;              // uint4 chunks per row (32 or 64)
  const int chl = (K == 512) ? 6 : 5;
  const int ksn = K >> 5;

  // stage A tile: 64 rows x ch chunks, swizzled chunk c -> c^(r&7)
  const int total = 64 << chl;
  for (int idx = tid; idx < total; idx += 256) {
    const int r = idx >> chl, c = idx & (ch - 1);
    const int m = m0 + r;
    const size_t arow = (size_t)(m >> TC_LOG_) * T_A + t0 + (m & (TC_ - 1));
    Ash[(r << chl) + (c ^ (r & 7))] =
        *(const uint4*)(A + arow * K + c * 8);
  }
  __syncthreads();

  const int lane = tid & 63;
  const int w = tid >> 6;              // wave = 16-col slice
  const int ar = lane & 15;
  const int koct = lane >> 4;
  const int nt = (n0 >> 4) + w;
  const short8v* wf = WF + (size_t)nt * ksn * 64 + lane;
  float4v acc0 = {0,0,0,0}, acc1 = {0,0,0,0}, acc2 = {0,0,0,0}, acc3 = {0,0,0,0};
#pragma unroll 4
  for (int ks = 0; ks < ksn; ++ks) {
    const short8v bv = wf[(size_t)ks * 64];
    const int cc = ks * 4 + koct;
    const short8v a0 = *(const short8v*)&Ash[((ar +  0) << chl) + (cc ^ ((ar +  0) & 7))];
    const short8v a1 = *(const short8v*)&Ash[((ar + 16) << chl) + (cc ^ ((ar + 16) & 7))];
    const short8v a2 = *(const short8v*)&Ash[((ar + 32) << chl) + (cc ^ ((ar + 32) & 7))];
    const short8v a3 = *(const short8v*)&Ash[((ar + 48) << chl) + (cc ^ ((ar + 48) & 7))];
    acc0 = __builtin_amdgcn_mfma_f32_16x16x32_bf16(a0, bv, acc0, 0, 0, 0);
    acc1 = __builtin_amdgcn_mfma_f32_16x16x32_bf16(a1, bv, acc1, 0, 0, 0);
    acc2 = __builtin_amdgcn_mfma_f32_16x16x32_bf16(a2, bv, acc2, 0, 0, 0);
    acc3 = __builtin_amdgcn_mfma_f32_16x16x32_bf16(a3, bv, acc3, 0, 0, 0);
  }
  // D layout: col = lane&15, row = (lane>>4)*4 + reg
  const int dcol = lane & 15, drow = (lane >> 4) * 4;
  const int n = n0 + w * 16 + dcol;
  const float bs = bias1[n] + bias2[n];
  float* Cb = C + (size_t)(m0 + drow) * G4_ + n;
#pragma unroll
  for (int rr = 0; rr < 4; ++rr) {
    Cb[(size_t)(0 + rr) * G4_]  = acc0[rr] + bs;
    Cb[(size_t)(16 + rr) * G4_] = acc1[rr] + bs;
    Cb[(size_t)(32 + rr) * G4_] = acc2[rr] + bs;
    Cb[(size_t)(48 + rr) * G4_] = acc3[rr] + bs;
  }
}

// ============================================================================
// Fused 2-layer MFMA LSTM step (verified round 7). mode 0: 512 blocks (L0+L1);
// 1: 256 L0; 2: 256 L1. Wave g computes gate g's 16x16 D over K=512.
// h0c dump is now bf16 (feeds the MFMA L1 GEMM); h1f stays fp32 for fc.
// ============================================================================
__global__ __launch_bounds__(256) void lstm_step2(
    const short8v* __restrict__ WF0, const float* __restrict__ xg0,
    const unsigned short* __restrict__ h0p, unsigned short* __restrict__ h0n,
    float* __restrict__ cs0, unsigned short* __restrict__ h0c,
    const short8v* __restrict__ WF1, const float* __restrict__ xg1,
    const unsigned short* __restrict__ h1p, unsigned short* __restrict__ h1n,
    float* __restrict__ cs1, float* __restrict__ h1f, int tl, int mode) {
  __shared__ unsigned short hsh[16 * 512];  // 16KB h tile (bf16, chunk-swizzled)
  __shared__ float gl[4][16][17];           // gate tiles for tail
  const int bid = blockIdx.x;
  const int layer = (mode == 0) ? (bid >> 8) : (mode - 1);
  const int xcd = bid & 7;
  const int ctl = (bid >> 3) & 3;
  const int bt  = (bid >> 5) & 7;
  const int ct  = xcd * 4 + ctl;
  const int b0  = bt * 16;

  const short8v* WF; const float* xg; const unsigned short* hprev;
  unsigned short* hnext; float* cst;
  if (layer == 0) { WF = WF0; xg = xg0; hprev = h0p; hnext = h0n; cst = cs0; }
  else            { WF = WF1; xg = xg1; hprev = h1p; hnext = h1n; cst = cs1; }

  const int tid = threadIdx.x;
  const int tb = tid >> 4, thc = tid & 15;
  const int bb = b0 + tb;
  const int hcol = ct * 16 + thc;
  const float* xr = xg + ((size_t)bb * TC_ + tl) * G4_ + hcol;
  const float xi = xr[0], xf = xr[512], xgv = xr[1024], xo = xr[1536];
  const float cin = cst[(size_t)bb * H_ + hcol];

  // stage h tile: 16 rows x 64 chunks(16B bf16x8), swizzle chunk c -> c^(r&7)
  const uint4* hp4 = (const uint4*)hprev + (size_t)b0 * 64;
#pragma unroll
  for (int j = 0; j < 4; ++j) {
    const int idx = tid + j * 256;
    const int r = idx >> 6, c = idx & 63;
    *(uint4*)&hsh[(r * 64 + (c ^ (r & 7))) * 8] = hp4[(size_t)r * 64 + c];
  }
  __syncthreads();

  const int lane = tid & 63;
  const int g = tid >> 6;
  const int ar = lane & 15;
  const int koct = lane >> 4;
  float4v acc = {0.f, 0.f, 0.f, 0.f};
  const short8v* wf = WF + ((size_t)(ct * 4 + g) * 16) * 64 + lane;
#pragma unroll
  for (int ks = 0; ks < 16; ++ks) {
    const int c16 = ks * 4 + koct;
    const short8v av = *(const short8v*)&hsh[(ar * 64 + (c16 ^ (ar & 7))) * 8];
    const short8v bv = wf[(size_t)ks * 64];
    acc = __builtin_amdgcn_mfma_f32_16x16x32_bf16(av, bv, acc, 0, 0, 0);
  }
  const int drow = (lane >> 4) * 4, dcol = lane & 15;
#pragma unroll
  for (int rr = 0; rr < 4; ++rr) gl[g][drow + rr][dcol] = acc[rr];
  __syncthreads();

  {
    const float gi = gl[0][tb][thc] + xi;
    const float gf = gl[1][tb][thc] + xf;
    const float gg = gl[2][tb][thc] + xgv;
    const float go = gl[3][tb][thc] + xo;
    const float iv = 1.f / (1.f + __expf(-gi));
    const float fv = 1.f / (1.f + __expf(-gf));
    const float gv = tanhf(gg);
    const float ov = 1.f / (1.f + __expf(-go));
    const float cn = fv * cin + iv * gv;
    const float hv = ov * tanhf(cn);
    cst[(size_t)bb * H_ + hcol] = cn;
    const unsigned short hb = (unsigned short)bfr(hv);
    hnext[(size_t)bb * H_ + hcol] = hb;
    if (layer == 0) h0c[((size_t)bb * TC_ + tl) * H_ + hcol] = hb;
    else            h1f[(size_t)bb * H_ + hcol] = hv;
  }
}

// ============================================================================
// Final FC (10 classes) + log_softmax. One wave per batch row (fp32 h).
// ============================================================================
__global__ __launch_bounds__(64) void fc_logsoftmax(
    const float* __restrict__ h, const float* __restrict__ Wfc,
    const float* __restrict__ bfc, float* __restrict__ out) {
  const int b = blockIdx.x, lane = threadIdx.x;
  const float4* h4 = (const float4*)(h + (size_t)b * H_);
  const float4 hv0 = h4[lane * 2], hv1 = h4[lane * 2 + 1];
  float logits[10];
#pragma unroll
  for (int cc = 0; cc < 10; ++cc) {
    const float4* w4 = (const float4*)(Wfc + (size_t)cc * H_);
    const float4 w0 = w4[lane * 2], w1 = w4[lane * 2 + 1];
    float v = hv0.x * w0.x + hv0.y * w0.y + hv0.z * w0.z + hv0.w * w0.w +
              hv1.x * w1.x + hv1.y * w1.y + hv1.z * w1.z + hv1.w * w1.w;
#pragma unroll
    for (int off = 32; off; off >>= 1) v += __shfl_xor(v, off);
    logits[cc] = v + bfc[cc];
  }
  float m = logits[0];
#pragma unroll
  for (int cc = 1; cc < 10; ++cc) m = fmaxf(m, logits[cc]);
  float s = 0.f;
#pragma unroll
  for (int cc = 0; cc < 10; ++cc) s += __expf(logits[cc] - m);
  const float lse = m + __logf(s);
  if (lane < 10) out[(size_t)b * 10 + lane] = logits[lane] - lse;
}

// ============================================================================
extern "C" void kernel_launch(void* const* d_in, const int* in_sizes, int n_in,
                              void* d_out, int out_size, void* d_ws, size_t ws_size,
                              hipStream_t stream) {
  const float* x    = (const float*)d_in[0];
  const float* Wih0 = (const float*)d_in[1];
  const float* Whh0 = (const float*)d_in[2];
  const float* bih0 = (const float*)d_in[3];
  const float* bhh0 = (const float*)d_in[4];
  const float* Wih1 = (const float*)d_in[5];
  const float* Whh1 = (const float*)d_in[6];
  const float* bih1 = (const float*)d_in[7];
  const float* bhh1 = (const float*)d_in[8];
  const float* Wfc  = (const float*)d_in[9];
  const float* bfc  = (const float*)d_in[10];

  float* ws   = (float*)d_ws;
  float* XG0  = ws + OFF_XG0;
  float* XG1  = ws + OFF_XG1;
  unsigned short* h0c = (unsigned short*)(ws + OFF_H0C);
  unsigned short* hb0 = (unsigned short*)(ws + OFF_HB0);
  unsigned short* hb1 = (unsigned short*)(ws + OFF_HB1);
  float* c0   = ws + OFF_C0;
  float* c1   = ws + OFF_C1;
  float* h1f  = ws + OFF_H1F;
  short8v* wf0 = (short8v*)(ws + OFF_WF0);
  short8v* wf1 = (short8v*)(ws + OFF_WF1);
  short8v* wi0 = (short8v*)(ws + OFF_WI0);
  short8v* wi1 = (short8v*)(ws + OFF_WI1);
  unsigned short* xbf = (unsigned short*)(ws + OFF_XBF);

  // zero h ping-pongs + c states; pack weights; convert x to bf16
  hipMemsetAsync(hb0, 0, (OFF_H1F - OFF_HB0) * sizeof(float), stream);
  pack_whh3<<<512, 256, 0, stream>>>(Whh0, (uint4*)wf0);
  pack_whh3<<<512, 256, 0, stream>>>(Whh1, (uint4*)wf1);
  pack_wih<<<256, 256, 0, stream>>>(Wih0, (uint4*)wi0, IN_);
  pack_wih<<<512, 256, 0, stream>>>(Wih1, (uint4*)wi1, H_);
  conv_bf16<<<4096, 256, 0, stream>>>(x, (uint4*)xbf, B_ * T_ * IN_ / 8);

  const size_t BHu = (size_t)B_ * H_;  // bf16 slot stride
  for (int ch = 0; ch < NCHUNK_; ++ch) {
    const int t0 = ch * TC_;
    gemm_xg_mfma<<<1024, 256, 0, stream>>>(xbf, wi0, bih0, bhh0, XG0, IN_, T_, t0);
    if (ch > 0)
      gemm_xg_mfma<<<1024, 256, 0, stream>>>(h0c, wi1, bih1, bhh1, XG1, H_, TC_, 0);
    for (int t = 0; t < TC_; ++t) {
      const int sg0 = t0 + t + 1;        // L0 global step (1-based)
      const int sg1 = sg0 - TC_;         // L1 global step (prev chunk)
      const int mode = (ch == 0) ? 1 : 0;
      const int nblk = (ch == 0) ? 256 : 512;
      lstm_step2<<<nblk, 256, 0, stream>>>(
          wf0, XG0, hb0 + ((sg0 - 1) & 1) * BHu, hb0 + (sg0 & 1) * BHu, c0, h0c,
          wf1, XG1, hb1 + ((sg1 - 1) & 1) * BHu, hb1 + (sg1 & 1) * BHu, c1, h1f,
          t, mode);
    }
  }
  // pipeline drain: L1 over the last chunk
  gemm_xg_mfma<<<1024, 256, 0, stream>>>(h0c, wi1, bih1, bhh1, XG1, H_, TC_, 0);
  for (int t = 0; t < TC_; ++t) {
    const int sg1 = (NCHUNK_ - 1) * TC_ + t + 1;
    lstm_step2<<<256, 256, 0, stream>>>(
        wf0, XG0, hb0, hb0, c0, h0c,
        wf1, XG1, hb1 + ((sg1 - 1) & 1) * BHu, hb1 + (sg1 & 1) * BHu, c1, h1f,
        t, 2);
  }
  fc_logsoftmax<<<dim3(B_), 64, 0, stream>>>(h1f, Wfc, bfc, (float*)d_out);
}